// Round 2
// baseline (1059.729 us; speedup 1.0000x reference)
//
#include <hip/hip_runtime.h>
#include <math.h>

#define Bn 131072
#define Dn 64
#define Kn 4096
#define TILE_R 128
#define TILE_K 128
#define NKT (Kn / TILE_K)

__device__ __forceinline__ int swz(int r) { return (r + (r >> 3)) & 7; }

// monotone float->uint key (ascending float -> ascending uint)
__device__ __forceinline__ unsigned fkey(float s) {
  unsigned u = __float_as_uint(s);
  return (u & 0x80000000u) ? ~u : (u | 0x80000000u);
}
// approximate inverse (low 12 bits were replaced by code)
__device__ __forceinline__ float unkey(unsigned u) {
  u &= 0xFFFFF000u;
  u = (u & 0x80000000u) ? (u ^ 0x80000000u) : ~u;
  return __uint_as_float(u);
}

__global__ __launch_bounds__(256) void vq_main(const float* __restrict__ z,
                                               const float* __restrict__ cb,
                                               float* __restrict__ out) {
  // 64 KiB exactly: zL 128x64, eL 128x64 (eL reused as candidate-key buffer).
  __shared__ float smem[16384];
  float* zL = smem;
  float* eL = smem + 8192;
  unsigned* redU = (unsigned*)eL;   // [row r][49 u32], 48 keys used

  const int tid = threadIdx.x;
  const int tx = tid & 15;
  const int ty = tid >> 4;
  const int row0 = blockIdx.x * TILE_R;

  // ---- stage z tile (row-major, 16B-unit xor swizzle) ----
  {
    const float4* z4 = (const float4*)(z + (size_t)row0 * Dn);
#pragma unroll
    for (int i = 0; i < 8; ++i) {
      int t = i * 256 + tid;
      int r = t >> 4, c4 = t & 15;
      float4 v = z4[t];
      *(float4*)(zL + r * 64 + ((c4 ^ swz(r)) << 2)) = v;
    }
  }

  // per-(thread,row) top-3 candidates as packed keys (ascending: K1<=K2<=K3)
  unsigned K1[8], K2[8], K3[8];
#pragma unroll
  for (int i = 0; i < 8; ++i) { K1[i] = 0xFFFFFFFFu; K2[i] = 0xFFFFFFFFu; K3[i] = 0xFFFFFFFFu; }

  for (int kt = 0; kt < NKT; ++kt) {
    const int k0 = kt * TILE_K;
    __syncthreads();   // prior-iter eL reads done (first iter: zL staging visible too)
    {
      const float4* c4p = (const float4*)(cb + (size_t)k0 * Dn);
#pragma unroll
      for (int i = 0; i < 8; ++i) {
        int t = i * 256 + tid;
        int lk = t >> 4, c4 = t & 15;
        float4 v = c4p[t];
        *(float4*)(eL + lk * 64 + ((c4 ^ swz(lk)) << 2)) = v;
      }
    }
    __syncthreads();

    float acc[8][8];
#pragma unroll
    for (int i = 0; i < 8; ++i)
#pragma unroll
      for (int j = 0; j < 8; ++j) acc[i][j] = 0.f;

    // swz(ty*8+i) == (ty+i)&7 ; swz(tx*8+j) == (tx+j)&7
#pragma unroll 2
    for (int dc = 0; dc < 16; ++dc) {
      float4 a4[8];
#pragma unroll
      for (int i = 0; i < 8; ++i)
        a4[i] = *(const float4*)(zL + (ty * 8 + i) * 64 + ((dc ^ ((ty + i) & 7)) << 2));
#pragma unroll
      for (int j = 0; j < 8; ++j) {
        float4 b4 = *(const float4*)(eL + (tx * 8 + j) * 64 + ((dc ^ ((tx + j) & 7)) << 2));
#pragma unroll
        for (int i = 0; i < 8; ++i) {
          acc[i][j] = fmaf(a4[i].x, b4.x, acc[i][j]);
          acc[i][j] = fmaf(a4[i].y, b4.y, acc[i][j]);
          acc[i][j] = fmaf(a4[i].z, b4.z, acc[i][j]);
          acc[i][j] = fmaf(a4[i].w, b4.w, acc[i][j]);
        }
      }
    }

    // ---- epilogue: group max of acc (score = -acc), insert into top-3 keys ----
    const int kb = k0 + tx * 8;
#pragma unroll
    for (int i = 0; i < 8; ++i) {
      float v0 = acc[i][0]; int x0 = 0;
      if (acc[i][1] > v0) { v0 = acc[i][1]; x0 = 1; }
      float v1 = acc[i][2]; int x1 = 2;
      if (acc[i][3] > v1) { v1 = acc[i][3]; x1 = 3; }
      float v2 = acc[i][4]; int x2 = 4;
      if (acc[i][5] > v2) { v2 = acc[i][5]; x2 = 5; }
      float v3 = acc[i][6]; int x3 = 6;
      if (acc[i][7] > v3) { v3 = acc[i][7]; x3 = 7; }
      if (v1 > v0) { v0 = v1; x0 = x1; }
      if (v3 > v2) { v2 = v3; x2 = x3; }
      if (v2 > v0) { v0 = v2; x0 = x2; }
      unsigned key = (fkey(-v0) & 0xFFFFF000u) | (unsigned)(kb + x0);
      if (key < K1[i]) { K3[i] = K2[i]; K2[i] = K1[i]; K1[i] = key; }
      else if (key < K2[i]) { K3[i] = K2[i]; K2[i] = key; }
      else if (key < K3[i]) { K3[i] = key; }
    }
  }

  __syncthreads();           // all eL reads done before reuse as key buffer
#pragma unroll
  for (int i = 0; i < 8; ++i) {
    int r = ty * 8 + i;
    unsigned* p = redU + r * 49 + tx * 3;
    p[0] = K1[i]; p[1] = K2[i]; p[2] = K3[i];
  }
  __syncthreads();

  if (tid < TILE_R) {
    const int r = tid;
    const int sr = swz(r);
    // z row into registers (de-swizzled, d-order)
    float4 zr[16];
#pragma unroll
    for (int g = 0; g < 16; ++g)
      zr[g] = *(const float4*)(zL + r * 64 + ((g ^ sr) << 2));

    // z2 = np-pairwise-64 f32 sum of fl32(z_d^2): 8 accumulators, ((r0+r1)+(r2+r3))+((r4+r5)+(r6+r7))
    float r8[8];
#pragma unroll
    for (int g = 0; g < 2; ++g) {
      float4 v = zr[g]; int j = g * 4;
      r8[j + 0] = __fmul_rn(v.x, v.x); r8[j + 1] = __fmul_rn(v.y, v.y);
      r8[j + 2] = __fmul_rn(v.z, v.z); r8[j + 3] = __fmul_rn(v.w, v.w);
    }
#pragma unroll
    for (int g = 2; g < 16; ++g) {
      float4 v = zr[g]; int j = (g & 1) * 4;
      r8[j + 0] = __fadd_rn(r8[j + 0], __fmul_rn(v.x, v.x));
      r8[j + 1] = __fadd_rn(r8[j + 1], __fmul_rn(v.y, v.y));
      r8[j + 2] = __fadd_rn(r8[j + 2], __fmul_rn(v.z, v.z));
      r8[j + 3] = __fadd_rn(r8[j + 3], __fmul_rn(v.w, v.w));
    }
    float z2f = __fadd_rn(__fadd_rn(__fadd_rn(r8[0], r8[1]), __fadd_rn(r8[2], r8[3])),
                          __fadd_rn(__fadd_rn(r8[4], r8[5]), __fadd_rn(r8[6], r8[7])));

    const unsigned* keys = redU + r * 49;
    unsigned mk = 0xFFFFFFFFu;
    for (int c = 0; c < 48; ++c) mk = min(mk, keys[c]);
    const float lim = unkey(mk) + 3.0e-5f;   // margin covers 2*ulp(64)/2 + trunc + fp32 noise

    float bq = INFINITY; int bc = Kn;
    for (int c = 0; c < 48; ++c) {
      unsigned key = keys[c];
      float sc = unkey(key);
      if (sc > lim) continue;
      int code = (int)(key & 0xFFFu);
      const float4* cr = (const float4*)(cb + (size_t)code * Dn);
      double ze = 0.0;
      float e8[8];
#pragma unroll
      for (int g = 0; g < 16; ++g) {
        float4 ev = cr[g];
        float4 zv = zr[g];
        ze += (double)ev.x * (double)zv.x + (double)ev.y * (double)zv.y +
              (double)ev.z * (double)zv.z + (double)ev.w * (double)zv.w;
        int j = (g & 1) * 4;
        if (g < 2) {
          e8[j + 0] = __fmul_rn(ev.x, ev.x); e8[j + 1] = __fmul_rn(ev.y, ev.y);
          e8[j + 2] = __fmul_rn(ev.z, ev.z); e8[j + 3] = __fmul_rn(ev.w, ev.w);
        } else {
          e8[j + 0] = __fadd_rn(e8[j + 0], __fmul_rn(ev.x, ev.x));
          e8[j + 1] = __fadd_rn(e8[j + 1], __fmul_rn(ev.y, ev.y));
          e8[j + 2] = __fadd_rn(e8[j + 2], __fmul_rn(ev.z, ev.z));
          e8[j + 3] = __fadd_rn(e8[j + 3], __fmul_rn(ev.w, ev.w));
        }
      }
      float e2f = __fadd_rn(__fadd_rn(__fadd_rn(e8[0], e8[1]), __fadd_rn(e8[2], e8[3])),
                            __fadd_rn(__fadd_rn(e8[4], e8[5]), __fadd_rn(e8[6], e8[7])));
      // np semantics: q = fl32( fl32(z2 + e2) - fl32(2*ze) ); 2*ze_f32 is exact
      float zef = (float)ze;
      float t1 = __fadd_rn(z2f, e2f);
      float t2 = __fmul_rn(2.0f, zef);
      float q = __fadd_rn(t1, -t2);
      if (q < bq || (q == bq && code < bc)) { bq = q; bc = code; }
    }
    redU[r * 49] = (unsigned)bc;                   // winner slot (own row only)
    out[(size_t)Bn * Dn + row0 + r] = (float)bc;   // codes as float
  }
  __syncthreads();

  // ---- gather z_q = cb[winner], coalesced float4 ----
  {
    const float4* cb4 = (const float4*)cb;
    float4* out4 = (float4*)out;
#pragma unroll
    for (int i = 0; i < 8; ++i) {
      int t = i * 256 + tid;
      int r = t >> 4, c = t & 15;
      int w = (int)redU[r * 49];
      out4[(size_t)(row0 + r) * 16 + c] = cb4[(size_t)w * 16 + c];
    }
  }
}

extern "C" void kernel_launch(void* const* d_in, const int* in_sizes, int n_in,
                              void* d_out, int out_size, void* d_ws, size_t ws_size,
                              hipStream_t stream) {
  const float* z = (const float*)d_in[0];
  const float* cb = (const float*)d_in[1];
  float* out = (float*)d_out;
  vq_main<<<Bn / TILE_R, 256, 0, stream>>>(z, cb, out);
}

// Round 4
// 220.344 us; speedup vs baseline: 4.8094x; 4.8094x over previous
//
#include <hip/hip_runtime.h>
#include <math.h>

#define Bn 131072
#define Dn 64
#define Kn 4096
#define TK 64              // codes per k-tile
#define NKT (Kn / TK)      // 64 tiles

typedef _Float16 f16x8 __attribute__((ext_vector_type(8)));
typedef float f32x4 __attribute__((ext_vector_type(4)));

__device__ __forceinline__ unsigned umn(unsigned a, unsigned b) { return a < b ? a : b; }
__device__ __forceinline__ unsigned umx(unsigned a, unsigned b) { return a > b ? a : b; }

// Single kernel: no d_ws, no global_load_lds, no multi-kernel ordering.
// score_collect = 256 + 4096*(-2 z.e)  (A=f16(-2z), B=f16(4096 e), C init=256)
// e2 omitted from collection (spread <= 2.6e-6 unscaled, margin covers); exact
// np-semantics recheck picks the final winner.
__global__ __launch_bounds__(256, 2) void vq_main(const float* __restrict__ z,
                                                  const float* __restrict__ cb,
                                                  float* __restrict__ out) {
  __shared__ __align__(16) unsigned char smem[33792];
  unsigned char* tb = smem;          // 8 KiB f16 tile image (aliased by dump later)
  const int tid = threadIdx.x;
  const int lane = tid & 63;
  const int w = tid >> 6;
  const int q = lane >> 4;
  const int col = lane & 15;
  const int row0 = blockIdx.x * 256;

  // ---- A fragments: f16(-2*z), register-resident; wave w owns rows w*64..+64
  // A[m=lane&15][k=q*8+j]
  f16x8 A[4][2];
#pragma unroll
  for (int i = 0; i < 4; ++i)
#pragma unroll
    for (int c = 0; c < 2; ++c) {
      const float* zp = z + (size_t)(row0 + w * 64 + i * 16 + col) * Dn + c * 32 + q * 8;
      float4 x0 = *(const float4*)zp;
      float4 x1 = *(const float4*)(zp + 4);
      f16x8 a;
      a[0] = (_Float16)(-2.f * x0.x); a[1] = (_Float16)(-2.f * x0.y);
      a[2] = (_Float16)(-2.f * x0.z); a[3] = (_Float16)(-2.f * x0.w);
      a[4] = (_Float16)(-2.f * x1.x); a[5] = (_Float16)(-2.f * x1.y);
      a[6] = (_Float16)(-2.f * x1.z); a[7] = (_Float16)(-2.f * x1.w);
      A[i][c] = a;
    }

  // staging role: thread -> (code n in tile, 16-dim chunk p); coalesced 64B/thread
  const int n = tid >> 2;
  const int p = tid & 3;
  const int wr0 = n * 128 + (((2 * p) ^ (n & 7)) << 4);
  const int wr1 = n * 128 + (((2 * p + 1) ^ (n & 7)) << 4);

  float4 pf0, pf1, pf2, pf3;   // register prefetch of next tile's f32 data
  {
    const float4* g = (const float4*)(cb + (size_t)n * Dn + p * 16);
    pf0 = g[0]; pf1 = g[1]; pf2 = g[2]; pf3 = g[3];
  }

  f32x4 acc[4][4];
  unsigned k1[4][4], k2[4][4];
#pragma unroll
  for (int i = 0; i < 4; ++i)
#pragma unroll
    for (int r = 0; r < 4; ++r) { k1[i][r] = 0xFFFFFFFFu; k2[i][r] = 0xFFFFFFFFu; }
  unsigned tg[4] = {0u, 1u, 2u, 3u};   // tag = kt*4 + t (8 bits)
  const f32x4 c256 = {256.f, 256.f, 256.f, 256.f};

  for (int kt = 0; kt < NKT; ++kt) {
    __syncthreads();               // all reads of previous tile image done
    // issue next tile's global loads first (latency hides behind this tile's compute)
    float4 nf0 = pf0, nf1 = pf1, nf2 = pf2, nf3 = pf3;
    if (kt + 1 < NKT) {
      const float4* g = (const float4*)(cb + ((size_t)(kt + 1) * TK + n) * Dn + p * 16);
      pf0 = g[0]; pf1 = g[1]; pf2 = g[2]; pf3 = g[3];
    }
    // convert current tile to f16 (x4096 exact scale) and write swizzled image
    {
      f16x8 h0, h1;
      h0[0] = (_Float16)(nf0.x * 4096.f); h0[1] = (_Float16)(nf0.y * 4096.f);
      h0[2] = (_Float16)(nf0.z * 4096.f); h0[3] = (_Float16)(nf0.w * 4096.f);
      h0[4] = (_Float16)(nf1.x * 4096.f); h0[5] = (_Float16)(nf1.y * 4096.f);
      h0[6] = (_Float16)(nf1.z * 4096.f); h0[7] = (_Float16)(nf1.w * 4096.f);
      h1[0] = (_Float16)(nf2.x * 4096.f); h1[1] = (_Float16)(nf2.y * 4096.f);
      h1[2] = (_Float16)(nf2.z * 4096.f); h1[3] = (_Float16)(nf2.w * 4096.f);
      h1[4] = (_Float16)(nf3.x * 4096.f); h1[5] = (_Float16)(nf3.y * 4096.f);
      h1[6] = (_Float16)(nf3.z * 4096.f); h1[7] = (_Float16)(nf3.w * 4096.f);
      *(f16x8*)(tb + wr0) = h0;
      *(f16x8*)(tb + wr1) = h1;
    }
    __syncthreads();               // image visible to all waves

#pragma unroll
    for (int c = 0; c < 2; ++c)
#pragma unroll
      for (int t = 0; t < 4; ++t) {
        // B[k=q*8+j][ncode=t*16+col]; unit (c*4+q) ^ (col&7)
        f16x8 Bf = *(const f16x8*)(tb + (t * 16 + col) * 128 + (((c * 4 + q) ^ (col & 7)) << 4));
#pragma unroll
        for (int i = 0; i < 4; ++i)
          acc[i][t] = __builtin_amdgcn_mfma_f32_16x16x32_f16(A[i][c], Bf,
                                                             (c == 0) ? c256 : acc[i][t], 0, 0, 0);
      }

    // epilogue: acc IS the positive score; key = (bits & ~0xFF) | tag; exact running top-2
#pragma unroll
    for (int i = 0; i < 4; ++i)
#pragma unroll
      for (int r = 0; r < 4; ++r) {
        unsigned K0 = (__float_as_uint(acc[i][0][r]) & 0xFFFFFF00u) | tg[0];
        unsigned K1v = (__float_as_uint(acc[i][1][r]) & 0xFFFFFF00u) | tg[1];
        unsigned K2v = (__float_as_uint(acc[i][2][r]) & 0xFFFFFF00u) | tg[2];
        unsigned K3v = (__float_as_uint(acc[i][3][r]) & 0xFFFFFF00u) | tg[3];
        unsigned lo = umn(K0, K1v), hi = umx(K0, K1v);
        k2[i][r] = umn(umn(k2[i][r], umx(k1[i][r], lo)), hi);
        k1[i][r] = umn(k1[i][r], lo);
        lo = umn(K2v, K3v); hi = umx(K2v, K3v);
        k2[i][r] = umn(umn(k2[i][r], umx(k1[i][r], lo)), hi);
        k1[i][r] = umn(k1[i][r], lo);
      }
#pragma unroll
    for (int t = 0; t < 4; ++t) tg[t] += 4;
  }

  __syncthreads();                 // compute done; reuse LDS for candidate dump
  unsigned* dmp = (unsigned*)smem; // wave w: [w*2048 + rr*32 + col*2 + {0,1}]
#pragma unroll
  for (int i = 0; i < 4; ++i)
#pragma unroll
    for (int r = 0; r < 4; ++r) {
      int rr = i * 16 + q * 4 + r;  // C-layout: row = quad*4 + reg within 16-row subtile
      dmp[w * 2048 + rr * 32 + col * 2] = k1[i][r];
      dmp[w * 2048 + rr * 32 + col * 2 + 1] = k2[i][r];
    }
  __syncthreads();

  // ---- final: per-row margin filter + exact np-semantics recheck ----
  {
    const int r = tid;
    const unsigned* keys = dmp + (r >> 6) * 2048 + (r & 63) * 32;
    unsigned mk = 0xFFFFFFFFu;
    for (int cnd = 0; cnd < 32; ++cnd) mk = umn(mk, keys[cnd]);
    // scaled margin 0.5 = 1.2e-4 unscaled: covers f16 cvt noise (RNE, ~5e-7),
    // e2 omission (2.6e-6), key truncation (1.9e-6), np fp32-grid ulp (7.6e-6)
    const float lim = __uint_as_float(mk & 0xFFFFFF00u) + 0.5f;

    const float4* zr4 = (const float4*)(z + (size_t)(row0 + r) * Dn);
    float4 zr[16];
#pragma unroll
    for (int g = 0; g < 16; ++g) zr[g] = zr4[g];

    // z2: np-pairwise grouping (argmin invariant to z2 rounding; keep R2-identical)
    float r8[8];
#pragma unroll
    for (int g = 0; g < 2; ++g) {
      float4 v = zr[g]; int j = g * 4;
      r8[j + 0] = __fmul_rn(v.x, v.x); r8[j + 1] = __fmul_rn(v.y, v.y);
      r8[j + 2] = __fmul_rn(v.z, v.z); r8[j + 3] = __fmul_rn(v.w, v.w);
    }
#pragma unroll
    for (int g = 2; g < 16; ++g) {
      float4 v = zr[g]; int j = (g & 1) * 4;
      r8[j + 0] = __fadd_rn(r8[j + 0], __fmul_rn(v.x, v.x));
      r8[j + 1] = __fadd_rn(r8[j + 1], __fmul_rn(v.y, v.y));
      r8[j + 2] = __fadd_rn(r8[j + 2], __fmul_rn(v.z, v.z));
      r8[j + 3] = __fadd_rn(r8[j + 3], __fmul_rn(v.w, v.w));
    }
    float z2f = __fadd_rn(__fadd_rn(__fadd_rn(r8[0], r8[1]), __fadd_rn(r8[2], r8[3])),
                          __fadd_rn(__fadd_rn(r8[4], r8[5]), __fadd_rn(r8[6], r8[7])));

    float bq = INFINITY; int bc = Kn;
    for (int cnd = 0; cnd < 32; ++cnd) {
      unsigned key = keys[cnd];
      float sc = __uint_as_float(key & 0xFFFFFF00u);
      if (sc > lim) continue;
      int tag = (int)(key & 0xFFu);
      int code = (tag >> 2) * 64 + (tag & 3) * 16 + (cnd >> 1);
      const float4* cr = (const float4*)(cb + (size_t)code * Dn);
      double ze = 0.0;
      float e8[8];
#pragma unroll
      for (int g = 0; g < 16; ++g) {
        float4 ev = cr[g]; float4 zv = zr[g];
        ze += (double)ev.x * (double)zv.x + (double)ev.y * (double)zv.y +
              (double)ev.z * (double)zv.z + (double)ev.w * (double)zv.w;
        int jj = (g & 1) * 4;
        if (g < 2) {
          e8[jj + 0] = __fmul_rn(ev.x, ev.x); e8[jj + 1] = __fmul_rn(ev.y, ev.y);
          e8[jj + 2] = __fmul_rn(ev.z, ev.z); e8[jj + 3] = __fmul_rn(ev.w, ev.w);
        } else {
          e8[jj + 0] = __fadd_rn(e8[jj + 0], __fmul_rn(ev.x, ev.x));
          e8[jj + 1] = __fadd_rn(e8[jj + 1], __fmul_rn(ev.y, ev.y));
          e8[jj + 2] = __fadd_rn(e8[jj + 2], __fmul_rn(ev.z, ev.z));
          e8[jj + 3] = __fadd_rn(e8[jj + 3], __fmul_rn(ev.w, ev.w));
        }
      }
      float e2f = __fadd_rn(__fadd_rn(__fadd_rn(e8[0], e8[1]), __fadd_rn(e8[2], e8[3])),
                            __fadd_rn(__fadd_rn(e8[4], e8[5]), __fadd_rn(e8[6], e8[7])));
      // np semantics: qv = fl32( fl32(z2 + e2) - fl32(2*ze) )
      float zef = (float)ze;
      float t1 = __fadd_rn(z2f, e2f);
      float t2 = __fmul_rn(2.0f, zef);
      float qv = __fadd_rn(t1, -t2);
      if (qv < bq || (qv == bq && code < bc)) { bq = qv; bc = code; }
    }
    ((int*)(smem + 32768))[r] = bc;
    out[(size_t)Bn * Dn + row0 + r] = (float)bc;
  }
  __syncthreads();

  // ---- gather z_q = cb[winner], coalesced float4 ----
  {
    const float4* cb4 = (const float4*)cb;
    float4* out4 = (float4*)out;
    const int* wc = (const int*)(smem + 32768);
#pragma unroll
    for (int i = 0; i < 16; ++i) {
      int t = i * 256 + tid;
      int r = t >> 4, c2 = t & 15;
      int wn = wc[r];
      out4[(size_t)(row0 + r) * 16 + c2] = cb4[(size_t)wn * 16 + c2];
    }
  }
}

extern "C" void kernel_launch(void* const* d_in, const int* in_sizes, int n_in,
                              void* d_out, int out_size, void* d_ws, size_t ws_size,
                              hipStream_t stream) {
  const float* z = (const float*)d_in[0];
  const float* cb = (const float*)d_in[1];
  float* out = (float*)d_out;
  vq_main<<<Bn / 256, 256, 0, stream>>>(z, cb, out);
}